// Round 14
// baseline (127.022 us; speedup 1.0000x reference)
//
#include <hip/hip_runtime.h>

#define NB 128
#define NS 65536

typedef float v2f __attribute__((ext_vector_type(2)));

// ---- packed f32 math (VOP3P: 2x f32 per issue) -----------------------------
__device__ __forceinline__ v2f pk_fma(v2f a, v2f b, v2f c) {
  v2f d;
  asm("v_pk_fma_f32 %0, %1, %2, %3" : "=v"(d) : "v"(a), "v"(b), "v"(c));
  return d;
}
__device__ __forceinline__ v2f pk_add(v2f a, v2f b) {
  v2f d;
  asm("v_pk_add_f32 %0, %1, %2" : "=v"(d) : "v"(a), "v"(b));
  return d;
}
__device__ __forceinline__ v2f pk_mul(v2f a, v2f b) {
  v2f d;
  asm("v_pk_mul_f32 %0, %1, %2" : "=v"(d) : "v"(a), "v"(b));
  return d;
}

// ---- VALU-pipe cross-lane helpers -----------------------------------------
template <int CTRL>
__device__ __forceinline__ float dppmov(float x) {
  return __int_as_float(__builtin_amdgcn_update_dpp(
      0, __float_as_int(x), CTRL, 0xF, 0xF, false));
}
__device__ __forceinline__ float xor4mov(float x) {
  int t = __builtin_amdgcn_update_dpp(0, __float_as_int(x), 0x104, 0xF, 0x5, false);
  t = __builtin_amdgcn_update_dpp(t, __float_as_int(x), 0x114, 0xF, 0xA, false);
  return __int_as_float(t);
}

// In-wave 256-point WHT on packed complex (re,im); zero DS-pipe ops.
__device__ __forceinline__ void wht256p(v2f (&p)[4], int lane) {
  const v2f M1 = {-1.f, -1.f};
  {
    v2f t;
    t = p[0]; p[0] = pk_add(t, p[1]); p[1] = pk_fma(M1, p[1], t);
    t = p[2]; p[2] = pk_add(t, p[3]); p[3] = pk_fma(M1, p[3], t);
    t = p[0]; p[0] = pk_add(t, p[2]); p[2] = pk_fma(M1, p[2], t);
    t = p[1]; p[1] = pk_add(t, p[3]); p[3] = pk_fma(M1, p[3], t);
  }
  const float s1f  = (lane & 1)  ? -1.f : 1.f;
  const float s2f  = (lane & 2)  ? -1.f : 1.f;
  const float s4f  = (lane & 4)  ? -1.f : 1.f;
  const float s8f  = (lane & 8)  ? -1.f : 1.f;
  const float s16f = (lane & 16) ? -1.f : 1.f;
  const float s32f = (lane & 32) ? -1.f : 1.f;
  const v2f s1 = {s1f, s1f}, s2 = {s2f, s2f}, s4 = {s4f, s4f};
  const v2f s8 = {s8f, s8f}, s16 = {s16f, s16f}, s32 = {s32f, s32f};
#pragma unroll
  for (int q = 0; q < 4; ++q) {
    v2f m = {dppmov<0xB1>(p[q].x), dppmov<0xB1>(p[q].y)};
    p[q] = pk_fma(s1, p[q], m);
  }
#pragma unroll
  for (int q = 0; q < 4; ++q) {
    v2f m = {dppmov<0x4E>(p[q].x), dppmov<0x4E>(p[q].y)};
    p[q] = pk_fma(s2, p[q], m);
  }
#pragma unroll
  for (int q = 0; q < 4; ++q) {
    v2f m = {xor4mov(p[q].x), xor4mov(p[q].y)};
    p[q] = pk_fma(s4, p[q], m);
  }
#pragma unroll
  for (int q = 0; q < 4; ++q) {
    v2f m = {dppmov<0x128>(p[q].x), dppmov<0x128>(p[q].y)};  // row_ror:8 == ^8
    p[q] = pk_fma(s8, p[q], m);
  }
#pragma unroll
  for (int q = 0; q < 4; ++q) {
    auto rre = __builtin_amdgcn_permlane16_swap(__float_as_uint(p[q].x),
                                                __float_as_uint(p[q].x), false, false);
    auto rim = __builtin_amdgcn_permlane16_swap(__float_as_uint(p[q].y),
                                                __float_as_uint(p[q].y), false, false);
    v2f lo = {__uint_as_float(rre[0]), __uint_as_float(rim[0])};
    v2f hi = {__uint_as_float(rre[1]), __uint_as_float(rim[1])};
    p[q] = pk_fma(s16, hi, lo);
  }
#pragma unroll
  for (int q = 0; q < 4; ++q) {
    auto rre = __builtin_amdgcn_permlane32_swap(__float_as_uint(p[q].x),
                                                __float_as_uint(p[q].x), false, false);
    auto rim = __builtin_amdgcn_permlane32_swap(__float_as_uint(p[q].y),
                                                __float_as_uint(p[q].y), false, false);
    v2f lo = {__uint_as_float(rre[0]), __uint_as_float(rim[0])};
    v2f hi = {__uint_as_float(rre[1]), __uint_as_float(rim[1])};
    p[q] = pk_fma(s32, hi, lo);
  }
}

// Fused kernel: 512 blocks x 1024 thr; block g = (batch b = g>>2, quad qd = g&3).
// Phase A: A_hi on 2 lo-tiles (32 lo each) -> T[b][m_hi][lo]; release cnt[b].
// Spin until cnt[b]==4 (all quads of batch done; all 512 blocks co-resident:
// 2/CU x 256 CU, and batch quads are contiguous in dispatch order -> safe).
// Phase B: A_lo + |.|^2 + permuted scatter on 64 m_hi rows.
__global__ __launch_bounds__(1024, 8) void fused_qsim(const float* __restrict__ sre,
                                                      const float* __restrict__ sim,
                                                      const float* __restrict__ thetas,
                                                      const int* __restrict__ cnot,
                                                      float* __restrict__ T,
                                                      float* __restrict__ partial,
                                                      int* __restrict__ cnt,
                                                      float* __restrict__ outp) {
  __shared__ float sr[32][260];
  __shared__ float si[32][260];
  __shared__ float2 phh4[64];
  __shared__ float2 phHQ[4];
  __shared__ float2 phl4[64];
  __shared__ float2 phLQ[4];
  __shared__ int sloL[64];
  __shared__ int tjs[16];
  __shared__ float red[16];
  __shared__ float ivs;
  const int g = blockIdx.x;
  const int b = g >> 2, qd = g & 3;
  const int tid = threadIdx.x, lane = tid & 63, w = tid >> 6;
  const float* pre = sre + ((size_t)b << 16);
  const float* pim = sim + ((size_t)b << 16);
  float* Tb = T + ((size_t)b << 17);
  const float* tb = thetas + b * 16;

  // ---- tables (independent of T) ----
  if (tid < 16) {
    int v = 0;
#pragma unroll
    for (int i = 0; i < 16; ++i) v |= ((cnot[1 << i] >> tid) & 1) << i;
    tjs[tid] = v;
  }
  if (tid < 64) {
    float a = 0.f, al = 0.f;
#pragma unroll
    for (int i = 0; i < 6; ++i)
      if ((tid >> (5 - i)) & 1) { a += tb[i]; al += tb[8 + i]; }
    phh4[tid] = make_float2(cosf(0.5f * a), -sinf(0.5f * a));
    phl4[tid] = make_float2(cosf(0.5f * al), -sinf(0.5f * al));
    if (tid < 4) {
      float aq = 0.f, aql = 0.f;
      if (tid & 1) { aq += tb[7]; aql += tb[15]; }
      if (tid & 2) { aq += tb[6]; aql += tb[14]; }
      phHQ[tid] = make_float2(cosf(0.5f * aq), -sinf(0.5f * aq));
      phLQ[tid] = make_float2(cosf(0.5f * aql), -sinf(0.5f * aql));
    }
  }

  // ---- phase A: 2 tiles of A_hi ----
  float accn = 0.f;
  const int c = tid & 7, jr = tid >> 3;
  // hoisted hi-phase factors
  float prqA[4], piqA[4];
#pragma unroll
  for (int t = 0; t < 2; ++t) {
    const int lo0 = (qd * 2 + t) * 32;
    const int j0 = jr, j1 = jr + 128;
    const float4 vr0 = *reinterpret_cast<const float4*>(pre + j0 * 256 + lo0 + c * 4);
    const float4 vi0 = *reinterpret_cast<const float4*>(pim + j0 * 256 + lo0 + c * 4);
    const float4 vr1 = *reinterpret_cast<const float4*>(pre + j1 * 256 + lo0 + c * 4);
    const float4 vi1 = *reinterpret_cast<const float4*>(pim + j1 * 256 + lo0 + c * 4);
    accn += vr0.x*vr0.x + vr0.y*vr0.y + vr0.z*vr0.z + vr0.w*vr0.w
          + vi0.x*vi0.x + vi0.y*vi0.y + vi0.z*vi0.z + vi0.w*vi0.w
          + vr1.x*vr1.x + vr1.y*vr1.y + vr1.z*vr1.z + vr1.w*vr1.w
          + vi1.x*vi1.x + vi1.y*vi1.y + vi1.z*vi1.z + vi1.w*vi1.w;
    {
      const int fs = ((c >> 1) & 3) << 2;
      const int j0s = j0 ^ fs, j1s = j1 ^ fs;
      sr[c*4+0][j0s] = vr0.x; sr[c*4+1][j0s] = vr0.y; sr[c*4+2][j0s] = vr0.z; sr[c*4+3][j0s] = vr0.w;
      si[c*4+0][j0s] = vi0.x; si[c*4+1][j0s] = vi0.y; si[c*4+2][j0s] = vi0.z; si[c*4+3][j0s] = vi0.w;
      sr[c*4+0][j1s] = vr1.x; sr[c*4+1][j1s] = vr1.y; sr[c*4+2][j1s] = vr1.z; sr[c*4+3][j1s] = vr1.w;
      si[c*4+0][j1s] = vi1.x; si[c*4+1][j1s] = vi1.y; si[c*4+2][j1s] = vi1.z; si[c*4+3][j1s] = vi1.w;
    }
    __syncthreads();
    if (t == 0) {
      // hoist per-(lane,q) hi-phase factors; sloL (needs tjs, now visible)
      const float2 p4 = phh4[lane];
#pragma unroll
      for (int q = 0; q < 4; ++q) {
        const float2 pq = phHQ[q];
        prqA[q] = p4.x * pq.x - p4.y * pq.y;
        piqA[q] = p4.x * pq.y + p4.y * pq.x;
      }
      if (tid < 64) {
        int v = 0;
#pragma unroll
        for (int bb = 0; bb < 6; ++bb)
          if ((tid >> bb) & 1) v ^= tjs[2 + bb];
        sloL[tid] = v;
      }
    }
    // compute: wave w owns rows 2w, 2w+1
#pragma unroll
    for (int r = 0; r < 2; ++r) {
      const int ll = w * 2 + r;
      const int blk = lane ^ ((ll >> 3) & 3);
      const float4 a4 = *reinterpret_cast<const float4*>(&sr[ll][blk * 4]);
      const float4 b4 = *reinterpret_cast<const float4*>(&si[ll][blk * 4]);
      v2f p[4] = {{a4.x, b4.x}, {a4.y, b4.y}, {a4.z, b4.z}, {a4.w, b4.w}};
      wht256p(p, lane);
#pragma unroll
      for (int q = 0; q < 4; ++q) {
        const float ur = p[q].x, ui = p[q].y;
        const v2f tt = pk_mul(p[q], (v2f){prqA[q], prqA[q]});
        p[q].x = fmaf(-piqA[q], ui, tt.x);
        p[q].y = fmaf(piqA[q], ur, tt.y);
      }
      wht256p(p, lane);
      *reinterpret_cast<float4*>(&sr[ll][blk * 4]) =
          make_float4(p[0].x, p[1].x, p[2].x, p[3].x);
      *reinterpret_cast<float4*>(&si[ll][blk * 4]) =
          make_float4(p[0].y, p[1].y, p[2].y, p[3].y);
    }
    __syncthreads();
    // drain: T[b][m][lo] complex interleaved
    const int m = tid >> 2, sub = tid & 3;
    float* dst = Tb + ((size_t)m << 9) + (size_t)lo0 * 2;
#pragma unroll
    for (int j = 0; j < 4; ++j) {
      const int l0 = 8 * j + 2 * sub;
      const int ms = m ^ ((j & 3) << 2);
      *reinterpret_cast<float4*>(dst + l0 * 2) =
          make_float4(sr[l0][ms], si[l0][ms], sr[l0 + 1][ms], si[l0 + 1][ms]);
    }
    __syncthreads();  // LDS reused next tile; also drains T stores (vmcnt 0)
  }
  // ---- norm partial + release ----
#pragma unroll
  for (int m2 = 32; m2 >= 1; m2 >>= 1) accn += __shfl_xor(accn, m2, 64);
  if (lane == 0) red[w] = accn;
  __syncthreads();
  if (tid == 0) {
    float sm = 0.f;
#pragma unroll
    for (int k = 0; k < 16; ++k) sm += red[k];
    partial[g] = sm;
    __threadfence();
    __hip_atomic_fetch_add(&cnt[b], 1, __ATOMIC_RELEASE, __HIP_MEMORY_SCOPE_AGENT);
  }
  // ---- acquire: wait for all 4 quads of this batch ----
  if (tid == 0) {
    while (__hip_atomic_load(&cnt[b], __ATOMIC_ACQUIRE, __HIP_MEMORY_SCOPE_AGENT) < 4)
      __builtin_amdgcn_s_sleep(8);
    const float s = partial[b * 4 + 0] + partial[b * 4 + 1] +
                    partial[b * 4 + 2] + partial[b * 4 + 3];
    ivs = 1.0f / (s * 4294967296.0f);  // fold 2^-32 WHT scaling + 1/norm^2
  }
  __syncthreads();
  // ---- phase B: A_lo + |.|^2 + permuted scatter on 64 m_hi rows ----
  const float iv = ivs;
  const float2 p4l = phl4[lane];
  const int sL = sloL[lane];
  const int sq1 = tjs[0], sq2 = tjs[1], sq3 = tjs[0] ^ tjs[1];
  float prq[4], piq[4];
#pragma unroll
  for (int q = 0; q < 4; ++q) {
    const float2 pq = phLQ[q];
    prq[q] = p4l.x * pq.x - p4l.y * pq.y;
    piq[q] = p4l.x * pq.y + p4l.y * pq.x;
  }
  float* ob = outp + ((size_t)b << 16);
#pragma unroll
  for (int r = 0; r < 4; ++r) {
    const int mh = qd * 64 + w * 4 + r;
    int srow = 0;
#pragma unroll
    for (int bb = 0; bb < 8; ++bb)
      if ((mh >> bb) & 1) srow ^= tjs[8 + bb];
    const float4 va = *reinterpret_cast<const float4*>(Tb + ((size_t)mh << 9) + lane * 8);
    const float4 vb = *reinterpret_cast<const float4*>(Tb + ((size_t)mh << 9) + lane * 8 + 4);
    v2f p[4] = {{va.x, va.y}, {va.z, va.w}, {vb.x, vb.y}, {vb.z, vb.w}};
    wht256p(p, lane);
#pragma unroll
    for (int q = 0; q < 4; ++q) {
      const float ur = p[q].x, ui = p[q].y;
      const v2f tt = pk_mul(p[q], (v2f){prq[q], prq[q]});
      p[q].x = fmaf(-piq[q], ui, tt.x);
      p[q].y = fmaf(piq[q], ur, tt.y);
    }
    wht256p(p, lane);
    const int base = srow ^ sL;
    const v2f m0 = pk_mul(p[0], p[0]);
    const v2f m1 = pk_mul(p[1], p[1]);
    const v2f m2 = pk_mul(p[2], p[2]);
    const v2f m3 = pk_mul(p[3], p[3]);
    ob[base]       = (m0.x + m0.y) * iv;
    ob[base ^ sq1] = (m1.x + m1.y) * iv;
    ob[base ^ sq2] = (m2.x + m2.y) * iv;
    ob[base ^ sq3] = (m3.x + m3.y) * iv;
  }
}

extern "C" void kernel_launch(void* const* d_in, const int* in_sizes, int n_in,
                              void* d_out, int out_size, void* d_ws, size_t ws_size,
                              hipStream_t stream) {
  const float* sre = (const float*)d_in[0];
  const float* sim = (const float*)d_in[1];
  const float* thetas = (const float*)d_in[2];
  const int* cnot = (const int*)d_in[3];
  float* outp = (float*)d_out;
  char* w = (char*)d_ws;
  const size_t CPLANE = (size_t)NB * NS * 2 * sizeof(float);  // 64 MB complex
  if (ws_size < CPLANE + 8192) return;
  float* T = (float*)(w);
  float* partial = (float*)(w + CPLANE);            // 512 floats
  int* cnt = (int*)(w + CPLANE + 2048);             // 128 ints

  hipMemsetAsync(cnt, 0, NB * sizeof(int), stream);
  hipLaunchKernelGGL(fused_qsim, dim3(512), dim3(1024), 0, stream,
                     sre, sim, thetas, cnot, T, partial, cnt, outp);
}

// Round 15
// 70.661 us; speedup vs baseline: 1.7976x; 1.7976x over previous
//
#include <hip/hip_runtime.h>

#define NB 128
#define NS 65536

typedef float v2f __attribute__((ext_vector_type(2)));

// ---- packed f32 math (VOP3P: 2x f32 per issue) -----------------------------
__device__ __forceinline__ v2f pk_fma(v2f a, v2f b, v2f c) {
  v2f d;
  asm("v_pk_fma_f32 %0, %1, %2, %3" : "=v"(d) : "v"(a), "v"(b), "v"(c));
  return d;
}
__device__ __forceinline__ v2f pk_add(v2f a, v2f b) {
  v2f d;
  asm("v_pk_add_f32 %0, %1, %2" : "=v"(d) : "v"(a), "v"(b));
  return d;
}
__device__ __forceinline__ v2f pk_mul(v2f a, v2f b) {
  v2f d;
  asm("v_pk_mul_f32 %0, %1, %2" : "=v"(d) : "v"(a), "v"(b));
  return d;
}

// ---- VALU-pipe cross-lane helpers -----------------------------------------
template <int CTRL>
__device__ __forceinline__ float dppmov(float x) {
  return __int_as_float(__builtin_amdgcn_update_dpp(
      0, __float_as_int(x), CTRL, 0xF, 0xF, false));
}
__device__ __forceinline__ float xor4mov(float x) {
  int t = __builtin_amdgcn_update_dpp(0, __float_as_int(x), 0x104, 0xF, 0x5, false);
  t = __builtin_amdgcn_update_dpp(t, __float_as_int(x), 0x114, 0xF, 0xA, false);
  return __int_as_float(t);
}

// In-wave 256-point WHT on packed complex (re,im); zero DS-pipe ops.
__device__ __forceinline__ void wht256p(v2f (&p)[4], int lane) {
  const v2f M1 = {-1.f, -1.f};
  {
    v2f t;
    t = p[0]; p[0] = pk_add(t, p[1]); p[1] = pk_fma(M1, p[1], t);
    t = p[2]; p[2] = pk_add(t, p[3]); p[3] = pk_fma(M1, p[3], t);
    t = p[0]; p[0] = pk_add(t, p[2]); p[2] = pk_fma(M1, p[2], t);
    t = p[1]; p[1] = pk_add(t, p[3]); p[3] = pk_fma(M1, p[3], t);
  }
  const float s1f  = (lane & 1)  ? -1.f : 1.f;
  const float s2f  = (lane & 2)  ? -1.f : 1.f;
  const float s4f  = (lane & 4)  ? -1.f : 1.f;
  const float s8f  = (lane & 8)  ? -1.f : 1.f;
  const float s16f = (lane & 16) ? -1.f : 1.f;
  const float s32f = (lane & 32) ? -1.f : 1.f;
  const v2f s1 = {s1f, s1f}, s2 = {s2f, s2f}, s4 = {s4f, s4f};
  const v2f s8 = {s8f, s8f}, s16 = {s16f, s16f}, s32 = {s32f, s32f};
#pragma unroll
  for (int q = 0; q < 4; ++q) {
    v2f m = {dppmov<0xB1>(p[q].x), dppmov<0xB1>(p[q].y)};
    p[q] = pk_fma(s1, p[q], m);
  }
#pragma unroll
  for (int q = 0; q < 4; ++q) {
    v2f m = {dppmov<0x4E>(p[q].x), dppmov<0x4E>(p[q].y)};
    p[q] = pk_fma(s2, p[q], m);
  }
#pragma unroll
  for (int q = 0; q < 4; ++q) {
    v2f m = {xor4mov(p[q].x), xor4mov(p[q].y)};
    p[q] = pk_fma(s4, p[q], m);
  }
#pragma unroll
  for (int q = 0; q < 4; ++q) {
    v2f m = {dppmov<0x128>(p[q].x), dppmov<0x128>(p[q].y)};  // row_ror:8 == ^8
    p[q] = pk_fma(s8, p[q], m);
  }
#pragma unroll
  for (int q = 0; q < 4; ++q) {
    auto rre = __builtin_amdgcn_permlane16_swap(__float_as_uint(p[q].x),
                                                __float_as_uint(p[q].x), false, false);
    auto rim = __builtin_amdgcn_permlane16_swap(__float_as_uint(p[q].y),
                                                __float_as_uint(p[q].y), false, false);
    v2f lo = {__uint_as_float(rre[0]), __uint_as_float(rim[0])};
    v2f hi = {__uint_as_float(rre[1]), __uint_as_float(rim[1])};
    p[q] = pk_fma(s16, hi, lo);
  }
#pragma unroll
  for (int q = 0; q < 4; ++q) {
    auto rre = __builtin_amdgcn_permlane32_swap(__float_as_uint(p[q].x),
                                                __float_as_uint(p[q].x), false, false);
    auto rim = __builtin_amdgcn_permlane32_swap(__float_as_uint(p[q].y),
                                                __float_as_uint(p[q].y), false, false);
    v2f lo = {__uint_as_float(rre[0]), __uint_as_float(rim[0])};
    v2f hi = {__uint_as_float(rre[1]), __uint_as_float(rim[1])};
    p[q] = pk_fma(s32, hi, lo);
  }
}

// K1: A_hi = WHT·diag(ph_hi)·WHT along the hi axis. Each block handles TWO
// 32-lo x 256-hi tiles; all 8 global float4 loads issued at kernel entry
// (tile-1 data in flight across tile-0's stage+compute). LDS float4-block
// swizzle (zero bank conflicts). Packed complex compute. Grid 512 (2/CU).
__global__ __launch_bounds__(1024, 8) void k1_ahi(const float* __restrict__ sre,
                                                  const float* __restrict__ sim,
                                                  const float* __restrict__ thetas,
                                                  float* __restrict__ T,
                                                  float* __restrict__ partial) {
  __shared__ float sr[32][260];
  __shared__ float si[32][260];
  __shared__ float2 phh4[64];
  __shared__ float2 phHQ[4];
  __shared__ float red[16];
  const int bid = blockIdx.x;
  const int b = bid >> 2, qd = bid & 3;
  const int lo0 = qd * 64, lo1 = lo0 + 32;
  const int tid = threadIdx.x, lane = tid & 63, w = tid >> 6;
  const float* pre = sre + ((size_t)b << 16);
  const float* pim = sim + ((size_t)b << 16);
  const int c = tid & 7, jr = tid >> 3;
  const int j0 = jr, j1 = jr + 128;
  // ---- prefetch ALL 8 float4s (both tiles, both rows, re+im) ----
  const float4 vr0 = *reinterpret_cast<const float4*>(pre + j0 * 256 + lo0 + c * 4);
  const float4 vi0 = *reinterpret_cast<const float4*>(pim + j0 * 256 + lo0 + c * 4);
  const float4 vr1 = *reinterpret_cast<const float4*>(pre + j1 * 256 + lo0 + c * 4);
  const float4 vi1 = *reinterpret_cast<const float4*>(pim + j1 * 256 + lo0 + c * 4);
  const float4 wr0 = *reinterpret_cast<const float4*>(pre + j0 * 256 + lo1 + c * 4);
  const float4 wi0 = *reinterpret_cast<const float4*>(pim + j0 * 256 + lo1 + c * 4);
  const float4 wr1 = *reinterpret_cast<const float4*>(pre + j1 * 256 + lo1 + c * 4);
  const float4 wi1 = *reinterpret_cast<const float4*>(pim + j1 * 256 + lo1 + c * 4);
  // phase tables (independent of loads)
  if (tid < 64) {
    const float* tb = thetas + b * 16;
    float a = 0.f;
#pragma unroll
    for (int i = 0; i < 6; ++i)
      if ((tid >> (5 - i)) & 1) a += tb[i];
    phh4[tid] = make_float2(cosf(0.5f * a), -sinf(0.5f * a));
    if (tid < 4) {
      float aq = 0.f;
      if (tid & 1) aq += tb[7];
      if (tid & 2) aq += tb[6];
      phHQ[tid] = make_float2(cosf(0.5f * aq), -sinf(0.5f * aq));
    }
  }
  // norm partial from registers (packed)
  v2f acc2 = {0.f, 0.f};
#define ACC4(f) do { \
    v2f u0 = {f.x, f.y}, u1 = {f.z, f.w}; \
    acc2 = pk_fma(u0, u0, acc2); acc2 = pk_fma(u1, u1, acc2); } while (0)
  ACC4(vr0); ACC4(vi0); ACC4(vr1); ACC4(vi1);
  ACC4(wr0); ACC4(wi0); ACC4(wr1); ACC4(wi1);
#undef ACC4
  float acc = acc2.x + acc2.y;
#pragma unroll
  for (int m2 = 32; m2 >= 1; m2 >>= 1) acc += __shfl_xor(acc, m2, 64);
  if (lane == 0) red[w] = acc;
  // ---- stage tile 0 (conflict-free swizzled transpose) ----
  const int fs = ((c >> 1) & 3) << 2;
  const int j0s = j0 ^ fs, j1s = j1 ^ fs;
  sr[c*4+0][j0s] = vr0.x; sr[c*4+1][j0s] = vr0.y; sr[c*4+2][j0s] = vr0.z; sr[c*4+3][j0s] = vr0.w;
  si[c*4+0][j0s] = vi0.x; si[c*4+1][j0s] = vi0.y; si[c*4+2][j0s] = vi0.z; si[c*4+3][j0s] = vi0.w;
  sr[c*4+0][j1s] = vr1.x; sr[c*4+1][j1s] = vr1.y; sr[c*4+2][j1s] = vr1.z; sr[c*4+3][j1s] = vr1.w;
  si[c*4+0][j1s] = vi1.x; si[c*4+1][j1s] = vi1.y; si[c*4+2][j1s] = vi1.z; si[c*4+3][j1s] = vi1.w;
  __syncthreads();
  if (tid == 0) {
    float sm = 0.f;
#pragma unroll
    for (int k = 0; k < 16; ++k) sm += red[k];
    partial[bid] = sm;
  }
  // hoisted per-(lane,q) hi-phase factors (reused for both tiles)
  const float2 p4 = phh4[lane];
  float prq[4], piq[4];
#pragma unroll
  for (int q = 0; q < 4; ++q) {
    const float2 pq = phHQ[q];
    prq[q] = p4.x * pq.x - p4.y * pq.y;
    piq[q] = p4.x * pq.y + p4.y * pq.x;
  }
  float* Tb = T + ((size_t)b << 17);
  const int mrow = tid >> 2, sub = tid & 3;
#pragma unroll
  for (int t = 0; t < 2; ++t) {
    // ---- compute: wave w owns rows 2w, 2w+1 ----
#pragma unroll
    for (int r = 0; r < 2; ++r) {
      const int ll = w * 2 + r;
      const int blk = lane ^ ((ll >> 3) & 3);
      const float4 a4 = *reinterpret_cast<const float4*>(&sr[ll][blk * 4]);
      const float4 b4 = *reinterpret_cast<const float4*>(&si[ll][blk * 4]);
      v2f p[4] = {{a4.x, b4.x}, {a4.y, b4.y}, {a4.z, b4.z}, {a4.w, b4.w}};
      wht256p(p, lane);
#pragma unroll
      for (int q = 0; q < 4; ++q) {
        const float ur = p[q].x, ui = p[q].y;
        const v2f tt = pk_mul(p[q], (v2f){prq[q], prq[q]});
        p[q].x = fmaf(-piq[q], ui, tt.x);
        p[q].y = fmaf(piq[q], ur, tt.y);
      }
      wht256p(p, lane);
      *reinterpret_cast<float4*>(&sr[ll][blk * 4]) =
          make_float4(p[0].x, p[1].x, p[2].x, p[3].x);
      *reinterpret_cast<float4*>(&si[ll][blk * 4]) =
          make_float4(p[0].y, p[1].y, p[2].y, p[3].y);
    }
    __syncthreads();
    // ---- drain: T[b][m][lo] complex interleaved ----
    float* dst = Tb + ((size_t)mrow << 9) + (size_t)(t == 0 ? lo0 : lo1) * 2;
#pragma unroll
    for (int j = 0; j < 4; ++j) {
      const int l0 = 8 * j + 2 * sub;
      const int ms = mrow ^ ((j & 3) << 2);
      *reinterpret_cast<float4*>(dst + l0 * 2) =
          make_float4(sr[l0][ms], si[l0][ms], sr[l0 + 1][ms], si[l0 + 1][ms]);
    }
    if (t == 0) {
      __syncthreads();
      // ---- stage tile 1 (regs loaded at kernel entry) ----
      sr[c*4+0][j0s] = wr0.x; sr[c*4+1][j0s] = wr0.y; sr[c*4+2][j0s] = wr0.z; sr[c*4+3][j0s] = wr0.w;
      si[c*4+0][j0s] = wi0.x; si[c*4+1][j0s] = wi0.y; si[c*4+2][j0s] = wi0.z; si[c*4+3][j0s] = wi0.w;
      sr[c*4+0][j1s] = wr1.x; sr[c*4+1][j1s] = wr1.y; sr[c*4+2][j1s] = wr1.z; sr[c*4+3][j1s] = wr1.w;
      si[c*4+0][j1s] = wi1.x; si[c*4+1][j1s] = wi1.y; si[c*4+2][j1s] = wi1.z; si[c*4+3][j1s] = wi1.w;
      __syncthreads();
    }
  }
}

// K2: A_lo = WHT·diag(ph_lo)·WHT along contiguous lo axis, |.|^2 * iv,
// permuted scatter. T row loads software-prefetched 2 rows ahead.
// XCD swizzle: each XCD owns 16 batches.
__global__ __launch_bounds__(256, 8) void k2_alo_scatter(const float* __restrict__ T,
                                                         const float* __restrict__ thetas,
                                                         const int* __restrict__ cnot,
                                                         const float* __restrict__ partial,
                                                         float* __restrict__ outp) {
  __shared__ float2 phl4[64];
  __shared__ float2 phLQ[4];
  __shared__ int sloL[64];
  __shared__ int tj[16];
  __shared__ int srow16[16];
  __shared__ float th[16];
  __shared__ float shinv;
  const int bid = blockIdx.x;
  const int x = bid & 7, s2i = bid >> 3;
  const int b = x * 16 + (s2i >> 4), tile = s2i & 15;
  const int tid = threadIdx.x, lane = tid & 63, w = tid >> 6;
  if (tid < 16) {
    th[tid] = thetas[b * 16 + tid];
    int v = 0;
#pragma unroll
    for (int i = 0; i < 16; ++i) v |= ((cnot[1 << i] >> tid) & 1) << i;
    tj[tid] = v;
  }
  if (tid == 0) {
    float sum = 0.f;
#pragma unroll
    for (int k = 0; k < 4; ++k) sum += partial[b * 4 + k];
    shinv = 1.0f / (sum * 4294967296.0f);  // fold 2^-32 WHT scaling + 1/norm^2
  }
  __syncthreads();
  if (tid < 64) {
    float a = 0.f;
#pragma unroll
    for (int i = 0; i < 6; ++i)
      if ((tid >> (5 - i)) & 1) a += th[8 + i];
    phl4[tid] = make_float2(cosf(0.5f * a), -sinf(0.5f * a));
    int v = 0;
#pragma unroll
    for (int bb = 0; bb < 6; ++bb)
      if ((tid >> bb) & 1) v ^= tj[2 + bb];
    sloL[tid] = v;
    if (tid < 4) {
      float aq = 0.f;
      if (tid & 1) aq += th[15];
      if (tid & 2) aq += th[14];
      phLQ[tid] = make_float2(cosf(0.5f * aq), -sinf(0.5f * aq));
    }
  }
  if (tid < 16) {
    const int mh = tile * 16 + tid;
    int v = 0;
#pragma unroll
    for (int bb = 0; bb < 8; ++bb)
      if ((mh >> bb) & 1) v ^= tj[8 + bb];
    srow16[tid] = v;
  }
  __syncthreads();
  const float* Tb = T + ((size_t)b << 17);
  float* ob = outp + ((size_t)b << 16);
  const float iv = shinv;
  const float2 p4 = phl4[lane];
  const int sL = sloL[lane];
  const int sq1 = tj[0], sq2 = tj[1], sq3 = tj[0] ^ tj[1];
  float prq[4], piq[4];
#pragma unroll
  for (int q = 0; q < 4; ++q) {
    const float2 pq = phLQ[q];
    prq[q] = p4.x * pq.x - p4.y * pq.y;
    piq[q] = p4.x * pq.y + p4.y * pq.x;
  }
  const float* rbase = Tb + ((size_t)(tile * 16 + w * 4) << 9) + lane * 8;
#define LDROW(A, B, r) \
  const float4 A = *reinterpret_cast<const float4*>(rbase + (r) * 512); \
  const float4 B = *reinterpret_cast<const float4*>(rbase + (r) * 512 + 4)
#define PROC(A, B, r) do { \
    v2f p[4] = {{A.x, A.y}, {A.z, A.w}, {B.x, B.y}, {B.z, B.w}}; \
    wht256p(p, lane); \
    _Pragma("unroll") \
    for (int q = 0; q < 4; ++q) { \
      const float ur = p[q].x, ui = p[q].y; \
      const v2f tt = pk_mul(p[q], (v2f){prq[q], prq[q]}); \
      p[q].x = fmaf(-piq[q], ui, tt.x); \
      p[q].y = fmaf(piq[q], ur, tt.y); \
    } \
    wht256p(p, lane); \
    const int base = srow16[w * 4 + (r)] ^ sL; \
    const v2f m0 = pk_mul(p[0], p[0]); \
    const v2f m1 = pk_mul(p[1], p[1]); \
    const v2f m2 = pk_mul(p[2], p[2]); \
    const v2f m3 = pk_mul(p[3], p[3]); \
    ob[base]       = (m0.x + m0.y) * iv; \
    ob[base ^ sq1] = (m1.x + m1.y) * iv; \
    ob[base ^ sq2] = (m2.x + m2.y) * iv; \
    ob[base ^ sq3] = (m3.x + m3.y) * iv; } while (0)
  LDROW(A0, B0, 0);
  LDROW(A1, B1, 1);
  LDROW(A2, B2, 2);
  PROC(A0, B0, 0);
  LDROW(A3, B3, 3);
  PROC(A1, B1, 1);
  PROC(A2, B2, 2);
  PROC(A3, B3, 3);
#undef LDROW
#undef PROC
}

extern "C" void kernel_launch(void* const* d_in, const int* in_sizes, int n_in,
                              void* d_out, int out_size, void* d_ws, size_t ws_size,
                              hipStream_t stream) {
  const float* sre = (const float*)d_in[0];
  const float* sim = (const float*)d_in[1];
  const float* thetas = (const float*)d_in[2];
  const int* cnot = (const int*)d_in[3];
  float* outp = (float*)d_out;
  char* w = (char*)d_ws;
  const size_t CPLANE = (size_t)NB * NS * 2 * sizeof(float);  // 64 MB complex
  if (ws_size < CPLANE + 8192) return;  // need 64 MB scratch + partials
  float* T = (float*)(w);
  float* partial = (float*)(w + CPLANE);  // 512 floats

  hipLaunchKernelGGL(k1_ahi, dim3(512), dim3(1024), 0, stream, sre, sim, thetas, T, partial);
  hipLaunchKernelGGL(k2_alo_scatter, dim3(2048), dim3(256), 0, stream, T, thetas, cnot, partial, outp);
}